// Round 12
// baseline (1804.789 us; speedup 1.0000x reference)
//
#include <hip/hip_runtime.h>

#define N_NODES 50000
#define N_EDGES 800000
#define HID 128
#define OUTC 10
#define N_GRAPHS 64
#define BN_EPS 1e-5f

#define MLP_BLOCKS (N_NODES / 16)   // 3125, exact

// radix partition params
#define NB 196          // ceil(50000/256) buckets of 256 nodes
#define BCAP 5632       // per-bucket capacity (mean 4096, sigma~64 -> +24 sigma)
#define EPB 2048        // edges per phase-A chunk
#define NBLK_A ((N_EDGES + EPB - 1) / EPB)   // 391

#define X2BF_ITEMS (N_NODES * HID / 8)           // 800000
#define PREP_ITEMS (X2BF_ITEMS + 6 * 2048)

#define GRID_BLKS 768   // 3 blocks/CU; launch_bounds(256,4) guarantees capacity 4 -> all resident
#define MPITCH 136
#define POOL_CHUNK 512
#define POOL_BLOCKS ((N_NODES + POOL_CHUNK - 1) / POOL_CHUNK)   // 98

typedef __attribute__((ext_vector_type(8))) short short8_t;
typedef __attribute__((ext_vector_type(4))) float f32x4;

__device__ __forceinline__ unsigned short f2bf(float f) {
    unsigned u = __float_as_uint(f);
    u += 0x7FFFu + ((u >> 16) & 1u);     // RNE
    return (unsigned short)(u >> 16);
}
__device__ __forceinline__ float bf2f(unsigned short s) {
    return __uint_as_float(((unsigned)s) << 16);
}
__device__ __forceinline__ float2 bfp2f(unsigned v) {
    float2 r;
    r.x = __uint_as_float(v << 16);
    r.y = __uint_as_float(v & 0xFFFF0000u);
    return r;
}

// Grid barrier: monotonically increasing target, no reset. threadfence BEFORE the
// block barrier releases all threads' writes (L2 writeback, agent scope = all XCDs);
// threadfence AFTER acquires (cache invalidate) so post-barrier reads are fresh.
__device__ __forceinline__ void grid_sync(unsigned* bar, unsigned target) {
    __threadfence();
    __syncthreads();
    if (threadIdx.x == 0) {
        __hip_atomic_fetch_add(bar, 1u, __ATOMIC_RELAXED, __HIP_MEMORY_SCOPE_AGENT);
        while (__hip_atomic_load(bar, __ATOMIC_RELAXED, __HIP_MEMORY_SCOPE_AGENT) < target)
            __builtin_amdgcn_s_sleep(8);
    }
    __syncthreads();
    __threadfence();
}

__global__ void __launch_bounds__(256, 4)
megak(const int* __restrict__ src, const int* __restrict__ dst,
      const float* __restrict__ x,
      const float* __restrict__ W1s, const float* __restrict__ b1s,
      const float* __restrict__ W2s, const float* __restrict__ b2s,
      const float* __restrict__ gammas, const float* __restrict__ betas,
      const float* __restrict__ Wlin, const float* __restrict__ blin,
      const int* __restrict__ batch,
      int* __restrict__ bucketCnt, unsigned* __restrict__ ebuf,
      unsigned short* __restrict__ srcSorted,
      int* __restrict__ estart, int* __restrict__ eend,
      unsigned short* __restrict__ Xbf, unsigned short* __restrict__ HA,
      unsigned short* __restrict__ HB, unsigned short* __restrict__ Wp,
      float* __restrict__ bnpart, float* __restrict__ bnsc,
      float* __restrict__ g, float* __restrict__ out,
      unsigned* __restrict__ bar)
{
    __shared__ __align__(16) unsigned short smem[2 * 16 * MPITCH];   // 8704 B, aliased per phase
    int t = threadIdx.x;
    int bx = blockIdx.x;
    unsigned sy = 0;

    // ================= Phase A: bucket binning (blocks 0..390) + prep (391..767) =================
    if (bx < NBLK_A) {
        int* cnt = (int*)smem;
        int* base = cnt + NB;
        for (int i = t; i < NB; i += 256) cnt[i] = 0;
        __syncthreads();
        int e0 = bx * EPB;
        int e1 = e0 + EPB; if (e1 > N_EDGES) e1 = N_EDGES;
        for (int e = e0 + t; e < e1; e += 256)
            atomicAdd(&cnt[dst[e] >> 8], 1);
        __syncthreads();
        for (int i = t; i < NB; i += 256) {
            int c = cnt[i];
            base[i] = c ? atomicAdd(&bucketCnt[i], c) : 0;
            cnt[i] = 0;
        }
        __syncthreads();
        for (int e = e0 + t; e < e1; e += 256) {
            int d = dst[e];
            int s = src[e];
            int b = d >> 8;
            int r = atomicAdd(&cnt[b], 1);
            ebuf[(size_t)b * BCAP + base[b] + r] = ((unsigned)(d & 255) << 16) | (unsigned)s;
        }
    } else {
        const int nPB = GRID_BLKS - NBLK_A;   // 377
        for (int gid = (bx - NBLK_A) * 256 + t; gid < PREP_ITEMS; gid += nPB * 256) {
            if (gid < X2BF_ITEMS) {
                const float4* p = (const float4*)&x[(size_t)gid * 8];
                float4 a = p[0], b = p[1];
                short8_t o = { (short)f2bf(a.x), (short)f2bf(a.y), (short)f2bf(a.z), (short)f2bf(a.w),
                               (short)f2bf(b.x), (short)f2bf(b.y), (short)f2bf(b.z), (short)f2bf(b.w) };
                *(short8_t*)&Xbf[(size_t)gid * 8] = o;
            } else {
                int idx = gid - X2BF_ITEMS;
                int mat = idx >> 11;
                int rem = idx & 2047;
                int lane = rem & 63;
                int ks = (rem >> 6) & 3;
                int nt = rem >> 8;
                int l = mat >> 1;
                const float* W = (mat & 1) ? (W2s + (size_t)l * HID * HID) : (W1s + (size_t)l * HID * HID);
                int n = nt * 16 + (lane & 15);
                int k0 = ks * 32 + (lane >> 4) * 8;
                short8_t o;
#pragma unroll
                for (int j = 0; j < 8; j++) o[j] = (short)f2bf(W[(size_t)(k0 + j) * HID + n]);
                *(short8_t*)&Wp[(size_t)idx * 8] = o;
            }
        }
    }
    grid_sync(bar, GRID_BLKS * ++sy);

    // ================= Phase B: per-bucket local sort =================
    for (int b = bx; b < NB; b += GRID_BLKS) {
        int* cnt = (int*)smem;
        int* sh  = cnt + 256;
        int* pos = cnt + 512;
        int n = bucketCnt[b];
        int bBase = b * BCAP;
        const unsigned* eb = ebuf + (size_t)bBase;
        cnt[t] = 0;
        __syncthreads();
        for (int i = t; i < n; i += 256) atomicAdd(&cnt[eb[i] >> 16], 1);
        __syncthreads();
        int v = cnt[t];
        sh[t] = v;
        __syncthreads();
        for (int off = 1; off < 256; off <<= 1) {
            int xv = sh[t];
            if (t >= off) xv += sh[t - off];
            __syncthreads();
            sh[t] = xv;
            __syncthreads();
        }
        int excl = sh[t] - v;
        pos[t] = excl;
        int node = b * 256 + t;
        if (node < N_NODES) {
            estart[node] = bBase + excl;
            eend[node] = bBase + excl + v;
        }
        __syncthreads();
        for (int i = t; i < n; i += 256) {
            unsigned pe = eb[i];
            int p = atomicAdd(&pos[pe >> 16], 1);
            srcSorted[bBase + p] = (unsigned short)(pe & 0xFFFFu);
        }
        __syncthreads();
    }
    grid_sync(bar, GRID_BLKS * ++sy);

    // ================= 3 layers: aggmlp (grid-stride tiles) + bnscale =================
    int lane = t & 63;
    int wave = t >> 6;
    int lrow = lane & 15;
    int quad = lane >> 4;
    int half = lane >> 5;
    int hl = lane & 31;
    int hq = hl >> 4;
    int col0 = lrow * 8;
    unsigned short* As = smem;
    unsigned short* Ts = smem + 16 * MPITCH;

    for (int l = 0; l < 3; l++) {
        const unsigned short* Xin = (l == 0) ? Xbf : ((l == 1) ? HA : HB);
        unsigned short* Hout = (l == 1) ? HB : HA;
        const bool useBN = (l > 0);
        const float* b1 = b1s + (size_t)l * HID;
        const float* b2 = b2s + (size_t)l * HID;
        const unsigned short* W1p = Wp + (size_t)(2 * l) * 16384;
        const unsigned short* W2p = Wp + (size_t)(2 * l + 1) * 16384;

        float scv[8], shv[8];
        if (useBN) {
#pragma unroll
            for (int j = 0; j < 8; j++) { scv[j] = bnsc[col0 + j]; shv[j] = bnsc[HID + col0 + j]; }
        } else {
#pragma unroll
            for (int j = 0; j < 8; j++) { scv[j] = 1.f; shv[j] = 0.f; }
        }

        for (int tile = bx; tile < MLP_BLOCKS; tile += GRID_BLKS) {
            int rowBase = tile * 16;

            // ---- gather: 2 pair-rounds; half-wave per node ----
            for (int pr = 0; pr < 2; pr++) {
                int tr = wave * 4 + pr * 2 + half;
                int node = rowBase + tr;
                float acc[8];
                {
                    short8_t ov = *(const short8_t*)&Xin[(size_t)node * HID + col0];
                    uint4 uu = *(uint4*)&ov;
                    float2 p0 = bfp2f(uu.x), p1 = bfp2f(uu.y), p2 = bfp2f(uu.z), p3 = bfp2f(uu.w);
                    float f[8] = { p0.x, p0.y, p1.x, p1.y, p2.x, p2.y, p3.x, p3.y };
#pragma unroll
                    for (int j = 0; j < 8; j++) {
                        float v = useBN ? fmaxf(f[j] * scv[j] + shv[j], 0.f) : f[j];
                        acc[j] = (hq == 0) ? v : 0.f;
                    }
                }

                int e0 = estart[node];
                int deg = eend[node] - e0;

                for (int base = 0; base < deg; base += 16) {
                    int cnt = deg - base; if (cnt > 16) cnt = 16;
                    int ipos = base + (hl & 15); if (ipos >= deg) ipos = deg - 1;
                    int myidx = (int)srcSorted[e0 + ipos];

                    short8_t v[8];
#pragma unroll
                    for (int u = 0; u < 8; u++) {
                        int slot = u * 2 + hq;
                        int sl = slot < cnt ? slot : cnt - 1;
                        int ridx = __shfl(myidx, (half << 5) + sl);
                        v[u] = *(const short8_t*)&Xin[(size_t)ridx * HID + col0];
                    }
#pragma unroll
                    for (int u = 0; u < 8; u++) {
                        int slot = u * 2 + hq;
                        if (slot < cnt) {
                            uint4 uu = *(uint4*)&v[u];
                            float2 p0 = bfp2f(uu.x), p1 = bfp2f(uu.y), p2 = bfp2f(uu.z), p3 = bfp2f(uu.w);
                            float f[8] = { p0.x, p0.y, p1.x, p1.y, p2.x, p2.y, p3.x, p3.y };
#pragma unroll
                            for (int j = 0; j < 8; j++)
                                acc[j] += useBN ? fmaxf(f[j] * scv[j] + shv[j], 0.f) : f[j];
                        }
                    }
                }

#pragma unroll
                for (int j = 0; j < 8; j++) acc[j] += __shfl_xor(acc[j], 16);
                if (hq == 0) {
                    short8_t o;
#pragma unroll
                    for (int j = 0; j < 8; j++) o[j] = (short)f2bf(acc[j]);
                    *(short8_t*)&As[tr * MPITCH + col0] = o;
                }
            }
            __syncthreads();   // As tile complete

            // ---- GEMM1: wave handles n-tiles {2*wave, 2*wave+1} ----
            int t0 = wave * 2;
            short8_t a0f = *(const short8_t*)&As[lrow * MPITCH + 0 * 32 + quad * 8];
            short8_t a1f = *(const short8_t*)&As[lrow * MPITCH + 1 * 32 + quad * 8];
            short8_t a2f = *(const short8_t*)&As[lrow * MPITCH + 2 * 32 + quad * 8];
            short8_t a3f = *(const short8_t*)&As[lrow * MPITCH + 3 * 32 + quad * 8];

            f32x4 acc1[2];
#pragma unroll
            for (int ti = 0; ti < 2; ti++) {
                int tt = t0 + ti;
                f32x4 a = (f32x4){ 0.f, 0.f, 0.f, 0.f };
                short8_t b0 = *(const short8_t*)&W1p[(size_t)((tt * 4 + 0) * 64 + lane) * 8];
                short8_t b1_ = *(const short8_t*)&W1p[(size_t)((tt * 4 + 1) * 64 + lane) * 8];
                short8_t b2_ = *(const short8_t*)&W1p[(size_t)((tt * 4 + 2) * 64 + lane) * 8];
                short8_t b3 = *(const short8_t*)&W1p[(size_t)((tt * 4 + 3) * 64 + lane) * 8];
                a = __builtin_amdgcn_mfma_f32_16x16x32_bf16(a0f, b0, a, 0, 0, 0);
                a = __builtin_amdgcn_mfma_f32_16x16x32_bf16(a1f, b1_, a, 0, 0, 0);
                a = __builtin_amdgcn_mfma_f32_16x16x32_bf16(a2f, b2_, a, 0, 0, 0);
                a = __builtin_amdgcn_mfma_f32_16x16x32_bf16(a3f, b3, a, 0, 0, 0);
                acc1[ti] = a;
            }

#pragma unroll
            for (int ti = 0; ti < 2; ti++) {
                int col = (t0 + ti) * 16 + lrow;
                float bb = b1[col];
#pragma unroll
                for (int r = 0; r < 4; r++) {
                    float v = fmaxf(acc1[ti][r] + bb, 0.f);
                    Ts[(quad * 4 + r) * MPITCH + col] = f2bf(v);
                }
            }
            __syncthreads();   // Ts complete

            // ---- GEMM2 ----
            short8_t t0f = *(const short8_t*)&Ts[lrow * MPITCH + 0 * 32 + quad * 8];
            short8_t t1f = *(const short8_t*)&Ts[lrow * MPITCH + 1 * 32 + quad * 8];
            short8_t t2f = *(const short8_t*)&Ts[lrow * MPITCH + 2 * 32 + quad * 8];
            short8_t t3f = *(const short8_t*)&Ts[lrow * MPITCH + 3 * 32 + quad * 8];

            f32x4 acc2[2];
#pragma unroll
            for (int ti = 0; ti < 2; ti++) {
                int tt = t0 + ti;
                f32x4 a = (f32x4){ 0.f, 0.f, 0.f, 0.f };
                short8_t b0 = *(const short8_t*)&W2p[(size_t)((tt * 4 + 0) * 64 + lane) * 8];
                short8_t b1_ = *(const short8_t*)&W2p[(size_t)((tt * 4 + 1) * 64 + lane) * 8];
                short8_t b2_ = *(const short8_t*)&W2p[(size_t)((tt * 4 + 2) * 64 + lane) * 8];
                short8_t b3 = *(const short8_t*)&W2p[(size_t)((tt * 4 + 3) * 64 + lane) * 8];
                a = __builtin_amdgcn_mfma_f32_16x16x32_bf16(t0f, b0, a, 0, 0, 0);
                a = __builtin_amdgcn_mfma_f32_16x16x32_bf16(t1f, b1_, a, 0, 0, 0);
                a = __builtin_amdgcn_mfma_f32_16x16x32_bf16(t2f, b2_, a, 0, 0, 0);
                a = __builtin_amdgcn_mfma_f32_16x16x32_bf16(t3f, b3, a, 0, 0, 0);
                acc2[ti] = a;
            }

#pragma unroll
            for (int ti = 0; ti < 2; ti++) {
                int tt = t0 + ti;
                int col = tt * 16 + lrow;
                float bb = b2[col];
                float p1 = 0.f, p2 = 0.f;
#pragma unroll
                for (int r = 0; r < 4; r++) {
                    unsigned short bv = f2bf(acc2[ti][r] + bb);
                    float vr = bf2f(bv);
                    p1 += vr; p2 += vr * vr;
                    As[(quad * 4 + r) * MPITCH + col] = bv;
                }
                p1 += __shfl_xor(p1, 16); p1 += __shfl_xor(p1, 32);
                p2 += __shfl_xor(p2, 16); p2 += __shfl_xor(p2, 32);
                if (quad == 0) {
                    float* bp = bnpart + (size_t)(tile & 63) * 256;
                    atomicAdd(&bp[col], p1);
                    atomicAdd(&bp[128 + col], p2);
                }
            }
            __syncthreads();   // C tile in As

            {
                int r = t >> 4;
                int c8 = (t & 15) * 8;
                *(short8_t*)&Hout[(size_t)(rowBase + r) * HID + c8] =
                    *(const short8_t*)&As[r * MPITCH + c8];
            }
            __syncthreads();   // As reads done before next tile's gather overwrites
        }
        grid_sync(bar, GRID_BLKS * ++sy);

        // ---- bnscale (block 0): reduce 64x256 -> sc; re-zero bnpart ----
        if (bx == 0) {
            float* tot = (float*)smem;
            float a = 0.f;
            for (int j = 0; j < 64; j++) a += bnpart[j * 256 + t];
            tot[t] = a;
            for (int j = 0; j < 64; j++) bnpart[j * 256 + t] = 0.f;
            __syncthreads();
            if (t < HID) {
                float mean = tot[t] * (1.0f / N_NODES);
                float var = tot[HID + t] * (1.0f / N_NODES) - mean * mean;
                float s = gammas[(size_t)l * HID + t] * rsqrtf(var + BN_EPS);
                bnsc[t] = s;
                bnsc[HID + t] = betas[(size_t)l * HID + t] - mean * s;
            }
            __syncthreads();
        }
        grid_sync(bar, GRID_BLKS * ++sy);
    }

    // ================= Pool (BN+ReLU fused; layer-2 output = HA) =================
    {
        int plane = t & 31;
        int prg = t >> 5;
        int c = plane * 4;
        float4 s4 = *(const float4*)&bnsc[c];
        float4 b4 = *(const float4*)&bnsc[HID + c];
        for (int chunk = bx; chunk < POOL_BLOCKS; chunk += GRID_BLKS) {
            int base = chunk * POOL_CHUNK;
            int end = base + POOL_CHUNK;
            if (end > N_NODES) end = N_NODES;
            float a0 = 0.f, a1 = 0.f, a2 = 0.f, a3 = 0.f;
            int cur = -1;
            for (int r = base + prg; r < end; r += 8) {
                int bb = batch[r];
                if (bb != cur) {
                    if (cur >= 0) {
                        atomicAdd(&g[cur * HID + c + 0], a0);
                        atomicAdd(&g[cur * HID + c + 1], a1);
                        atomicAdd(&g[cur * HID + c + 2], a2);
                        atomicAdd(&g[cur * HID + c + 3], a3);
                    }
                    cur = bb;
                    a0 = a1 = a2 = a3 = 0.f;
                }
                ushort4 v = *(const ushort4*)&HA[(size_t)r * HID + c];
                a0 += fmaxf(bf2f(v.x) * s4.x + b4.x, 0.f);
                a1 += fmaxf(bf2f(v.y) * s4.y + b4.y, 0.f);
                a2 += fmaxf(bf2f(v.z) * s4.z + b4.z, 0.f);
                a3 += fmaxf(bf2f(v.w) * s4.w + b4.w, 0.f);
            }
            if (cur >= 0) {
                atomicAdd(&g[cur * HID + c + 0], a0);
                atomicAdd(&g[cur * HID + c + 1], a1);
                atomicAdd(&g[cur * HID + c + 2], a2);
                atomicAdd(&g[cur * HID + c + 3], a3);
            }
        }
    }
    grid_sync(bar, GRID_BLKS * ++sy);

    // ================= Final linear (block 0) =================
    if (bx == 0) {
        for (int o = t; o < N_GRAPHS * OUTC; o += 256) {
            int gi = o / OUTC, cc = o % OUTC;
            float acc = blin[cc];
            for (int k = 0; k < HID; k++) acc += g[gi * HID + k] * Wlin[k * OUTC + cc];
            out[o] = acc;
        }
    }
}

// ---------------- Launch ----------------
extern "C" void kernel_launch(void* const* d_in, const int* in_sizes, int n_in,
                              void* d_out, int out_size, void* d_ws, size_t ws_size,
                              hipStream_t stream) {
    const float* x      = (const float*)d_in[0];
    const float* W1s    = (const float*)d_in[1];
    const float* b1s    = (const float*)d_in[2];
    const float* W2s    = (const float*)d_in[3];
    const float* b2s    = (const float*)d_in[4];
    const float* gammas = (const float*)d_in[5];
    const float* betas  = (const float*)d_in[6];
    const float* Wlin   = (const float*)d_in[7];
    const float* blin   = (const float*)d_in[8];
    const int* edge_index = (const int*)d_in[9];
    const int* batch    = (const int*)d_in[10];
    float* out = (float*)d_out;

    const int* src = edge_index;
    const int* dst = edge_index + N_EDGES;

    char* w = (char*)d_ws;
    // zeroed region (single memset): bar | bucketCnt | bnpart | g
    unsigned* bar  = (unsigned*)w;   w += 16;
    int* bucketCnt = (int*)w;        w += 256 * 4;
    float* bnpart  = (float*)w;      w += (size_t)64 * 256 * 4;          // 64 KB
    float* g       = (float*)w;      w += (size_t)N_GRAPHS * HID * 4;    // 32 KB
    size_t zeroBytes = (size_t)(w - (char*)d_ws);
    // rest
    unsigned* ebuf = (unsigned*)w;   w += (size_t)NB * BCAP * 4;         // 4.4 MB
    unsigned short* srcSorted = (unsigned short*)w; w += (size_t)NB * BCAP * 2; // 2.2 MB
    int* estart    = (int*)w;        w += (size_t)N_NODES * 4;
    int* eend      = (int*)w;        w += (size_t)N_NODES * 4;
    unsigned short* Xbf = (unsigned short*)w; w += (size_t)N_NODES * HID * 2;   // 12.8 MB
    unsigned short* HA  = (unsigned short*)w; w += (size_t)N_NODES * HID * 2;
    unsigned short* HB  = (unsigned short*)w; w += (size_t)N_NODES * HID * 2;
    unsigned short* Wp  = (unsigned short*)w; w += (size_t)6 * 2048 * 8 * 2;
    float* bnsc   = (float*)w; w += 2 * HID * 4;

    hipMemsetAsync(d_ws, 0, zeroBytes, stream);

    megak<<<GRID_BLKS, 256, 0, stream>>>(
        src, dst, x, W1s, b1s, W2s, b2s, gammas, betas, Wlin, blin, batch,
        bucketCnt, ebuf, srcSorted, estart, eend,
        Xbf, HA, HB, Wp, bnpart, bnsc, g, out, bar);
}

// Round 13
// 285.759 us; speedup vs baseline: 6.3158x; 6.3158x over previous
//
#include <hip/hip_runtime.h>

#define N_NODES 50000
#define N_EDGES 800000
#define HID 128
#define OUTC 10
#define N_GRAPHS 64
#define BN_EPS 1e-5f

#define MLP_BLOCKS (N_NODES / 16)   // 3125, exact

// radix partition params
#define NB 196          // ceil(50000/256) buckets of 256 nodes
#define BCAP 5632       // per-bucket capacity (mean 4082; huge margin)
#define EPB 2048        // edges per phase-A block
#define NBLK_A ((N_EDGES + EPB - 1) / EPB)   // 391

#define X2BF_ITEMS (N_NODES * HID / 8)           // 800000
#define PREP_ITEMS (X2BF_ITEMS + 6 * 2048)
#define NBLK_PREP ((PREP_ITEMS + 255) / 256)

#define BN_SLOTS 8      // bnpart slots per layer; 3125/8 = 390 atomics/addr over 45us
#define BN_REGION (BN_SLOTS * 256)   // floats per layer region

typedef __attribute__((ext_vector_type(8))) short short8_t;
typedef __attribute__((ext_vector_type(4))) float f32x4;

__device__ __forceinline__ unsigned short f2bf(float f) {
    unsigned u = __float_as_uint(f);
    u += 0x7FFFu + ((u >> 16) & 1u);     // RNE
    return (unsigned short)(u >> 16);
}
__device__ __forceinline__ float bf2f(unsigned short s) {
    return __uint_as_float(((unsigned)s) << 16);
}
__device__ __forceinline__ float2 bfp2f(unsigned v) {
    float2 r;
    r.x = __uint_as_float(v << 16);
    r.y = __uint_as_float(v & 0xFFFF0000u);
    return r;
}

// ---------------- Fused: phase-A bucket binning + (x->bf16, weight pre-pack) ----------------
__global__ __launch_bounds__(256) void k_bucketprep(const int* __restrict__ src,
                                                    const int* __restrict__ dst,
                                                    int* __restrict__ bucketCnt,
                                                    unsigned* __restrict__ ebuf,
                                                    const float* __restrict__ x,
                                                    const float* __restrict__ W1s,
                                                    const float* __restrict__ W2s,
                                                    unsigned short* __restrict__ xbf,
                                                    unsigned short* __restrict__ Wp) {
    int t = threadIdx.x;
    if (blockIdx.x < NBLK_A) {
        __shared__ int cnt[NB];
        __shared__ int base[NB];
        for (int i = t; i < NB; i += 256) cnt[i] = 0;
        __syncthreads();
        int e0 = blockIdx.x * EPB;
        int e1 = e0 + EPB; if (e1 > N_EDGES) e1 = N_EDGES;
        for (int e = e0 + t; e < e1; e += 256)
            atomicAdd(&cnt[dst[e] >> 8], 1);
        __syncthreads();
        for (int i = t; i < NB; i += 256) {
            int c = cnt[i];
            base[i] = c ? atomicAdd(&bucketCnt[i], c) : 0;
            cnt[i] = 0;
        }
        __syncthreads();
        for (int e = e0 + t; e < e1; e += 256) {
            int d = dst[e];
            int s = src[e];
            int b = d >> 8;
            int r = atomicAdd(&cnt[b], 1);
            ebuf[(size_t)b * BCAP + base[b] + r] = ((unsigned)(d & 255) << 16) | (unsigned)s;
        }
    } else {
        int gid = (blockIdx.x - NBLK_A) * 256 + t;
        if (gid < X2BF_ITEMS) {
            const float4* p = (const float4*)&x[(size_t)gid * 8];
            float4 a = p[0], b = p[1];
            short8_t o = { (short)f2bf(a.x), (short)f2bf(a.y), (short)f2bf(a.z), (short)f2bf(a.w),
                           (short)f2bf(b.x), (short)f2bf(b.y), (short)f2bf(b.z), (short)f2bf(b.w) };
            *(short8_t*)&xbf[(size_t)gid * 8] = o;
        } else {
            int idx = gid - X2BF_ITEMS;
            if (idx >= 6 * 2048) return;
            int mat = idx >> 11;
            int rem = idx & 2047;
            int lane = rem & 63;
            int ks = (rem >> 6) & 3;
            int nt = rem >> 8;
            int l = mat >> 1;
            const float* W = (mat & 1) ? (W2s + (size_t)l * HID * HID) : (W1s + (size_t)l * HID * HID);
            int n = nt * 16 + (lane & 15);
            int k0 = ks * 32 + (lane >> 4) * 8;
            short8_t o;
#pragma unroll
            for (int j = 0; j < 8; j++) o[j] = (short)f2bf(W[(size_t)(k0 + j) * HID + n]);
            *(short8_t*)&Wp[(size_t)idx * 8] = o;
        }
    }
}

// ---------------- Phase B: per-bucket local sort -> srcSorted + estart/eend ----------------
__global__ __launch_bounds__(256) void k_bsort(const int* __restrict__ bucketCnt,
                                               const unsigned* __restrict__ ebuf,
                                               unsigned short* __restrict__ srcSorted,
                                               int* __restrict__ estart,
                                               int* __restrict__ eend) {
    __shared__ int cnt[256];
    __shared__ int sh[256];
    __shared__ int pos[256];
    int b = blockIdx.x;
    int t = threadIdx.x;
    int n = bucketCnt[b];
    int bBase = b * BCAP;
    const unsigned* eb = ebuf + (size_t)bBase;
    cnt[t] = 0;
    __syncthreads();
    for (int i = t; i < n; i += 256) atomicAdd(&cnt[eb[i] >> 16], 1);
    __syncthreads();
    int v = cnt[t];
    sh[t] = v;
    __syncthreads();
    for (int off = 1; off < 256; off <<= 1) {
        int x = sh[t];
        if (t >= off) x += sh[t - off];
        __syncthreads();
        sh[t] = x;
        __syncthreads();
    }
    int excl = sh[t] - v;
    pos[t] = excl;
    int node = b * 256 + t;
    if (node < N_NODES) {
        estart[node] = bBase + excl;
        eend[node] = bBase + excl + v;
    }
    __syncthreads();
    for (int i = t; i < n; i += 256) {
        unsigned pe = eb[i];
        int dl = pe >> 16;
        int p = atomicAdd(&pos[dl], 1);
        srcSorted[bBase + p] = (unsigned short)(pe & 0xFFFFu);
    }
}

// ---------------- Fused aggregation + MFMA MLP, BN-scale computed in-kernel ----------------
#define MPITCH 136

template <bool BN>
__global__ __launch_bounds__(256) void k_aggmlp(const unsigned short* __restrict__ X,
                                                const float* __restrict__ bnprev,   // prev layer's bnpart region
                                                const float* __restrict__ gamma,
                                                const float* __restrict__ beta,
                                                const int* __restrict__ estart,
                                                const int* __restrict__ eend,
                                                const unsigned short* __restrict__ srcSorted,
                                                const unsigned short* __restrict__ W1p,
                                                const float* __restrict__ b1,
                                                const unsigned short* __restrict__ W2p,
                                                const float* __restrict__ b2,
                                                unsigned short* __restrict__ hbf,
                                                float* __restrict__ bnout) {
    __shared__ __align__(16) unsigned short As[16 * MPITCH];
    __shared__ __align__(16) unsigned short Ts[16 * MPITCH];

    int tid = threadIdx.x;
    int wave = tid >> 6;
    int lane = tid & 63;
    int lrow = lane & 15;
    int quad = lane >> 4;
    int half = lane >> 5;
    int hl = lane & 31;
    int hq = hl >> 4;
    int rowBase = blockIdx.x * 16;
    int col0 = lrow * 8;

    float scv[8], shv[8];
    if (BN) {
        // redundant per-block BN finalize from prev layer's partials (8 KB, L2-hot)
        float* ft = (float*)As;          // 256 floats
        float* scs = ft + 256;           // 256 floats: sc[0..127], shift[0..127]
        float a = 0.f;
#pragma unroll
        for (int j = 0; j < BN_SLOTS; j++) a += bnprev[j * 256 + tid];
        ft[tid] = a;
        __syncthreads();
        if (tid < HID) {
            float mean = ft[tid] * (1.0f / N_NODES);
            float var = ft[HID + tid] * (1.0f / N_NODES) - mean * mean;
            float s = gamma[tid] * rsqrtf(var + BN_EPS);
            scs[tid] = s;
            scs[HID + tid] = beta[tid] - mean * s;
        }
        __syncthreads();
#pragma unroll
        for (int j = 0; j < 8; j++) { scv[j] = scs[col0 + j]; shv[j] = scs[HID + col0 + j]; }
        __syncthreads();   // done with As-as-float scratch before gather writes As
    }

    for (int pr = 0; pr < 2; pr++) {
        int tr = wave * 4 + pr * 2 + half;
        int node = rowBase + tr;
        float acc[8];
        {
            short8_t ov = *(const short8_t*)&X[(size_t)node * HID + col0];
            uint4 uu = *(uint4*)&ov;
            float2 p0 = bfp2f(uu.x), p1 = bfp2f(uu.y), p2 = bfp2f(uu.z), p3 = bfp2f(uu.w);
            float f[8] = { p0.x, p0.y, p1.x, p1.y, p2.x, p2.y, p3.x, p3.y };
#pragma unroll
            for (int j = 0; j < 8; j++) {
                float v = BN ? fmaxf(f[j] * scv[j] + shv[j], 0.f) : f[j];
                acc[j] = (hq == 0) ? v : 0.f;
            }
        }

        int e0 = estart[node];
        int deg = eend[node] - e0;

        for (int base = 0; base < deg; base += 16) {
            int cnt = deg - base; if (cnt > 16) cnt = 16;
            int ipos = base + (hl & 15); if (ipos >= deg) ipos = deg - 1;
            int myidx = (int)srcSorted[e0 + ipos];

            short8_t v[8];
#pragma unroll
            for (int u = 0; u < 8; u++) {
                int slot = u * 2 + hq;
                int sl = slot < cnt ? slot : cnt - 1;
                int ridx = __shfl(myidx, (half << 5) + sl);
                v[u] = *(const short8_t*)&X[(size_t)ridx * HID + col0];
            }
#pragma unroll
            for (int u = 0; u < 8; u++) {
                int slot = u * 2 + hq;
                if (slot < cnt) {
                    uint4 uu = *(uint4*)&v[u];
                    float2 p0 = bfp2f(uu.x), p1 = bfp2f(uu.y), p2 = bfp2f(uu.z), p3 = bfp2f(uu.w);
                    float f[8] = { p0.x, p0.y, p1.x, p1.y, p2.x, p2.y, p3.x, p3.y };
#pragma unroll
                    for (int j = 0; j < 8; j++)
                        acc[j] += BN ? fmaxf(f[j] * scv[j] + shv[j], 0.f) : f[j];
                }
            }
        }

#pragma unroll
        for (int j = 0; j < 8; j++) acc[j] += __shfl_xor(acc[j], 16);
        if (hq == 0) {
            short8_t o;
#pragma unroll
            for (int j = 0; j < 8; j++) o[j] = (short)f2bf(acc[j]);
            *(short8_t*)&As[tr * MPITCH + col0] = o;
        }
    }
    __syncthreads();

    int t0 = wave * 2;
    short8_t a0f = *(const short8_t*)&As[lrow * MPITCH + 0 * 32 + quad * 8];
    short8_t a1f = *(const short8_t*)&As[lrow * MPITCH + 1 * 32 + quad * 8];
    short8_t a2f = *(const short8_t*)&As[lrow * MPITCH + 2 * 32 + quad * 8];
    short8_t a3f = *(const short8_t*)&As[lrow * MPITCH + 3 * 32 + quad * 8];

    f32x4 acc1[2];
#pragma unroll
    for (int ti = 0; ti < 2; ti++) {
        int t = t0 + ti;
        f32x4 a = (f32x4){ 0.f, 0.f, 0.f, 0.f };
        short8_t b0 = *(const short8_t*)&W1p[(size_t)((t * 4 + 0) * 64 + lane) * 8];
        short8_t b1_ = *(const short8_t*)&W1p[(size_t)((t * 4 + 1) * 64 + lane) * 8];
        short8_t b2_ = *(const short8_t*)&W1p[(size_t)((t * 4 + 2) * 64 + lane) * 8];
        short8_t b3 = *(const short8_t*)&W1p[(size_t)((t * 4 + 3) * 64 + lane) * 8];
        a = __builtin_amdgcn_mfma_f32_16x16x32_bf16(a0f, b0, a, 0, 0, 0);
        a = __builtin_amdgcn_mfma_f32_16x16x32_bf16(a1f, b1_, a, 0, 0, 0);
        a = __builtin_amdgcn_mfma_f32_16x16x32_bf16(a2f, b2_, a, 0, 0, 0);
        a = __builtin_amdgcn_mfma_f32_16x16x32_bf16(a3f, b3, a, 0, 0, 0);
        acc1[ti] = a;
    }

#pragma unroll
    for (int ti = 0; ti < 2; ti++) {
        int col = (t0 + ti) * 16 + lrow;
        float bb = b1[col];
#pragma unroll
        for (int r = 0; r < 4; r++) {
            float v = fmaxf(acc1[ti][r] + bb, 0.f);
            Ts[(quad * 4 + r) * MPITCH + col] = f2bf(v);
        }
    }
    __syncthreads();

    short8_t t0f = *(const short8_t*)&Ts[lrow * MPITCH + 0 * 32 + quad * 8];
    short8_t t1f = *(const short8_t*)&Ts[lrow * MPITCH + 1 * 32 + quad * 8];
    short8_t t2f = *(const short8_t*)&Ts[lrow * MPITCH + 2 * 32 + quad * 8];
    short8_t t3f = *(const short8_t*)&Ts[lrow * MPITCH + 3 * 32 + quad * 8];

    f32x4 acc2[2];
#pragma unroll
    for (int ti = 0; ti < 2; ti++) {
        int t = t0 + ti;
        f32x4 a = (f32x4){ 0.f, 0.f, 0.f, 0.f };
        short8_t b0 = *(const short8_t*)&W2p[(size_t)((t * 4 + 0) * 64 + lane) * 8];
        short8_t b1_ = *(const short8_t*)&W2p[(size_t)((t * 4 + 1) * 64 + lane) * 8];
        short8_t b2_ = *(const short8_t*)&W2p[(size_t)((t * 4 + 2) * 64 + lane) * 8];
        short8_t b3 = *(const short8_t*)&W2p[(size_t)((t * 4 + 3) * 64 + lane) * 8];
        a = __builtin_amdgcn_mfma_f32_16x16x32_bf16(t0f, b0, a, 0, 0, 0);
        a = __builtin_amdgcn_mfma_f32_16x16x32_bf16(t1f, b1_, a, 0, 0, 0);
        a = __builtin_amdgcn_mfma_f32_16x16x32_bf16(t2f, b2_, a, 0, 0, 0);
        a = __builtin_amdgcn_mfma_f32_16x16x32_bf16(t3f, b3, a, 0, 0, 0);
        acc2[ti] = a;
    }

#pragma unroll
    for (int ti = 0; ti < 2; ti++) {
        int t = t0 + ti;
        int col = t * 16 + lrow;
        float bb = b2[col];
        float p1 = 0.f, p2 = 0.f;
#pragma unroll
        for (int r = 0; r < 4; r++) {
            unsigned short bv = f2bf(acc2[ti][r] + bb);
            float vr = bf2f(bv);
            p1 += vr; p2 += vr * vr;
            As[(quad * 4 + r) * MPITCH + col] = bv;
        }
        p1 += __shfl_xor(p1, 16); p1 += __shfl_xor(p1, 32);
        p2 += __shfl_xor(p2, 16); p2 += __shfl_xor(p2, 32);
        if (quad == 0) {
            float* bp = bnout + (size_t)(blockIdx.x & (BN_SLOTS - 1)) * 256;
            atomicAdd(&bp[col], p1);
            atomicAdd(&bp[128 + col], p2);
        }
    }
    __syncthreads();

    {
        int r = tid >> 4;
        int c8 = (tid & 15) * 8;
        *(short8_t*)&hbf[(size_t)(rowBase + r) * HID + c8] =
            *(const short8_t*)&As[r * MPITCH + c8];
    }
}

// ---------------- Pool with in-kernel BN finalize + fused BN+ReLU ----------------
#define POOL_CHUNK 512
__global__ void k_pool(const unsigned short* __restrict__ X, const float* __restrict__ bnprev,
                       const float* __restrict__ gamma, const float* __restrict__ beta,
                       const int* __restrict__ batch, float* __restrict__ g) {
    __shared__ float scs[512];   // tot then sc/shift
    int t = threadIdx.x;
    {
        float a = 0.f;
#pragma unroll
        for (int j = 0; j < BN_SLOTS; j++) a += bnprev[j * 256 + t];
        scs[t] = a;
        __syncthreads();
        if (t < HID) {
            float mean = scs[t] * (1.0f / N_NODES);
            float var = scs[HID + t] * (1.0f / N_NODES) - mean * mean;
            float s = gamma[t] * rsqrtf(var + BN_EPS);
            float sh = beta[t] - mean * s;
            scs[t] = s;
            scs[HID + t] = sh;
        }
        __syncthreads();
    }
    int lane = t & 31;
    int rg = t >> 5;
    int c = lane * 4;
    float4 s = *(const float4*)&scs[c];
    float4 b = *(const float4*)&scs[HID + c];
    int base = blockIdx.x * POOL_CHUNK;
    int end = base + POOL_CHUNK;
    if (end > N_NODES) end = N_NODES;
    float a0 = 0.f, a1 = 0.f, a2 = 0.f, a3 = 0.f;
    int cur = -1;
    for (int r = base + rg; r < end; r += 8) {
        int bb = batch[r];
        if (bb != cur) {
            if (cur >= 0) {
                atomicAdd(&g[cur * HID + c + 0], a0);
                atomicAdd(&g[cur * HID + c + 1], a1);
                atomicAdd(&g[cur * HID + c + 2], a2);
                atomicAdd(&g[cur * HID + c + 3], a3);
            }
            cur = bb;
            a0 = a1 = a2 = a3 = 0.f;
        }
        ushort4 v = *(const ushort4*)&X[(size_t)r * HID + c];
        a0 += fmaxf(bf2f(v.x) * s.x + b.x, 0.f);
        a1 += fmaxf(bf2f(v.y) * s.y + b.y, 0.f);
        a2 += fmaxf(bf2f(v.z) * s.z + b.z, 0.f);
        a3 += fmaxf(bf2f(v.w) * s.w + b.w, 0.f);
    }
    if (cur >= 0) {
        atomicAdd(&g[cur * HID + c + 0], a0);
        atomicAdd(&g[cur * HID + c + 1], a1);
        atomicAdd(&g[cur * HID + c + 2], a2);
        atomicAdd(&g[cur * HID + c + 3], a3);
    }
}

// ---------------- Final linear ----------------
__global__ void k_final(const float* __restrict__ g, const float* __restrict__ Wlin,
                        const float* __restrict__ blin, float* __restrict__ out) {
    int o = blockIdx.x * 256 + threadIdx.x;
    if (o >= N_GRAPHS * OUTC) return;
    int gi = o / OUTC, c = o % OUTC;
    float s = blin[c];
    for (int k = 0; k < HID; k++) s += g[gi * HID + k] * Wlin[k * OUTC + c];
    out[o] = s;
}

// ---------------- Launch ----------------
extern "C" void kernel_launch(void* const* d_in, const int* in_sizes, int n_in,
                              void* d_out, int out_size, void* d_ws, size_t ws_size,
                              hipStream_t stream) {
    const float* x      = (const float*)d_in[0];
    const float* W1s    = (const float*)d_in[1];
    const float* b1s    = (const float*)d_in[2];
    const float* W2s    = (const float*)d_in[3];
    const float* b2s    = (const float*)d_in[4];
    const float* gammas = (const float*)d_in[5];
    const float* betas  = (const float*)d_in[6];
    const float* Wlin   = (const float*)d_in[7];
    const float* blin   = (const float*)d_in[8];
    const int* edge_index = (const int*)d_in[9];
    const int* batch    = (const int*)d_in[10];
    float* out = (float*)d_out;

    const int* src = edge_index;
    const int* dst = edge_index + N_EDGES;

    char* w = (char*)d_ws;
    // zeroed region (single memset): bucketCnt | bnpart (3 regions) | g
    int* bucketCnt = (int*)w;        w += 256 * 4;
    float* bnpart  = (float*)w;      w += (size_t)3 * BN_REGION * 4;     // 24 KB
    float* g       = (float*)w;      w += (size_t)N_GRAPHS * HID * 4;    // 32 KB
    size_t zeroBytes = (size_t)(w - (char*)d_ws);
    // rest
    unsigned* ebuf = (unsigned*)w;   w += (size_t)NB * BCAP * 4;         // 4.4 MB
    unsigned short* srcSorted = (unsigned short*)w; w += (size_t)NB * BCAP * 2; // 2.2 MB
    int* estart    = (int*)w;        w += (size_t)N_NODES * 4;
    int* eend      = (int*)w;        w += (size_t)N_NODES * 4;
    unsigned short* Xbf = (unsigned short*)w; w += (size_t)N_NODES * HID * 2;   // 12.8 MB
    unsigned short* HA  = (unsigned short*)w; w += (size_t)N_NODES * HID * 2;
    unsigned short* HB  = (unsigned short*)w; w += (size_t)N_NODES * HID * 2;
    unsigned short* Wp  = (unsigned short*)w; w += (size_t)6 * 2048 * 8 * 2;

    hipMemsetAsync(d_ws, 0, zeroBytes, stream);

    k_bucketprep<<<NBLK_A + NBLK_PREP, 256, 0, stream>>>(src, dst, bucketCnt, ebuf,
                                                         x, W1s, W2s, Xbf, Wp);
    k_bsort<<<NB, 256, 0, stream>>>(bucketCnt, ebuf, srcSorted, estart, eend);

    // layer 0: Xbf -> HA ; layer 1: HA -> HB ; layer 2: HB -> HA
    const unsigned short* in0 = Xbf;
    unsigned short* outs[3] = { HA, HB, HA };
    for (int l = 0; l < 3; l++) {
        const unsigned short* xin = (l == 0) ? in0 : outs[l - 1];
        float* bnout = bnpart + (size_t)l * BN_REGION;
        if (l == 0)
            k_aggmlp<false><<<MLP_BLOCKS, 256, 0, stream>>>(
                xin, nullptr, nullptr, nullptr, estart, eend, srcSorted,
                Wp + (size_t)(l * 2 + 0) * 16384, b1s + (size_t)l * HID,
                Wp + (size_t)(l * 2 + 1) * 16384, b2s + (size_t)l * HID, outs[l], bnout);
        else
            k_aggmlp<true><<<MLP_BLOCKS, 256, 0, stream>>>(
                xin, bnpart + (size_t)(l - 1) * BN_REGION,
                gammas + (size_t)(l - 1) * HID, betas + (size_t)(l - 1) * HID,
                estart, eend, srcSorted,
                Wp + (size_t)(l * 2 + 0) * 16384, b1s + (size_t)l * HID,
                Wp + (size_t)(l * 2 + 1) * 16384, b2s + (size_t)l * HID, outs[l], bnout);
    }

    k_pool<<<(N_NODES + POOL_CHUNK - 1) / POOL_CHUNK, 256, 0, stream>>>(
        outs[2], bnpart + (size_t)2 * BN_REGION, gammas + (size_t)2 * HID,
        betas + (size_t)2 * HID, batch, g);
    k_final<<<(N_GRAPHS * OUTC + 255) / 256, 256, 0, stream>>>(g, Wlin, blin, out);
}

// Round 14
// 283.386 us; speedup vs baseline: 6.3687x; 1.0084x over previous
//
#include <hip/hip_runtime.h>

#define N_NODES 50000
#define N_EDGES 800000
#define HID 128
#define OUTC 10
#define N_GRAPHS 64
#define BN_EPS 1e-5f

#define MLP_BLOCKS (N_NODES / 16)   // 3125, exact

// radix partition params
#define NB 196          // ceil(50000/256) buckets of 256 nodes
#define BCAP 5632       // per-bucket capacity (mean 4082; huge margin)
#define EPB 2048        // edges per phase-A block
#define NBLK_A ((N_EDGES + EPB - 1) / EPB)   // 391

#define X2BF_ITEMS (N_NODES * HID / 8)           // 800000
#define PREP_ITEMS (X2BF_ITEMS + 6 * 2048)
#define NBLK_PREP ((PREP_ITEMS + 255) / 256)

#define BN_SLOTS 8
#define BN_REGION (BN_SLOTS * 256)

typedef __attribute__((ext_vector_type(8))) short short8_t;
typedef __attribute__((ext_vector_type(4))) float f32x4;

__device__ __forceinline__ unsigned short f2bf(float f) {
    unsigned u = __float_as_uint(f);
    u += 0x7FFFu + ((u >> 16) & 1u);     // RNE
    return (unsigned short)(u >> 16);
}
__device__ __forceinline__ float bf2f(unsigned short s) {
    return __uint_as_float(((unsigned)s) << 16);
}
__device__ __forceinline__ float2 bfp2f(unsigned v) {
    float2 r;
    r.x = __uint_as_float(v << 16);
    r.y = __uint_as_float(v & 0xFFFF0000u);
    return r;
}

// ---------------- Fused: phase-A bucket binning + (x->bf16, weight pre-pack) ----------------
__global__ __launch_bounds__(256) void k_bucketprep(const int* __restrict__ src,
                                                    const int* __restrict__ dst,
                                                    int* __restrict__ bucketCnt,
                                                    unsigned* __restrict__ ebuf,
                                                    const float* __restrict__ x,
                                                    const float* __restrict__ W1s,
                                                    const float* __restrict__ W2s,
                                                    unsigned short* __restrict__ xbf,
                                                    unsigned short* __restrict__ Wp) {
    int t = threadIdx.x;
    if (blockIdx.x < NBLK_A) {
        __shared__ int cnt[NB];
        __shared__ int base[NB];
        for (int i = t; i < NB; i += 256) cnt[i] = 0;
        __syncthreads();
        int e0 = blockIdx.x * EPB;
        int e1 = e0 + EPB; if (e1 > N_EDGES) e1 = N_EDGES;
        for (int e = e0 + t; e < e1; e += 256)
            atomicAdd(&cnt[dst[e] >> 8], 1);
        __syncthreads();
        for (int i = t; i < NB; i += 256) {
            int c = cnt[i];
            base[i] = c ? atomicAdd(&bucketCnt[i], c) : 0;
            cnt[i] = 0;
        }
        __syncthreads();
        for (int e = e0 + t; e < e1; e += 256) {
            int d = dst[e];
            int s = src[e];
            int b = d >> 8;
            int r = atomicAdd(&cnt[b], 1);
            ebuf[(size_t)b * BCAP + base[b] + r] = ((unsigned)(d & 255) << 16) | (unsigned)s;
        }
    } else {
        int gid = (blockIdx.x - NBLK_A) * 256 + t;
        if (gid < X2BF_ITEMS) {
            const float4* p = (const float4*)&x[(size_t)gid * 8];
            float4 a = p[0], b = p[1];
            short8_t o = { (short)f2bf(a.x), (short)f2bf(a.y), (short)f2bf(a.z), (short)f2bf(a.w),
                           (short)f2bf(b.x), (short)f2bf(b.y), (short)f2bf(b.z), (short)f2bf(b.w) };
            *(short8_t*)&xbf[(size_t)gid * 8] = o;
        } else {
            int idx = gid - X2BF_ITEMS;
            if (idx >= 6 * 2048) return;
            int mat = idx >> 11;
            int rem = idx & 2047;
            int lane = rem & 63;
            int ks = (rem >> 6) & 3;
            int nt = rem >> 8;
            int l = mat >> 1;
            const float* W = (mat & 1) ? (W2s + (size_t)l * HID * HID) : (W1s + (size_t)l * HID * HID);
            int n = nt * 16 + (lane & 15);
            int k0 = ks * 32 + (lane >> 4) * 8;
            short8_t o;
#pragma unroll
            for (int j = 0; j < 8; j++) o[j] = (short)f2bf(W[(size_t)(k0 + j) * HID + n]);
            *(short8_t*)&Wp[(size_t)idx * 8] = o;
        }
    }
}

// ---------------- Phase B: per-bucket local sort -> srcSorted + estart/eend ----------------
__global__ __launch_bounds__(256) void k_bsort(const int* __restrict__ bucketCnt,
                                               const unsigned* __restrict__ ebuf,
                                               unsigned short* __restrict__ srcSorted,
                                               int* __restrict__ estart,
                                               int* __restrict__ eend) {
    __shared__ int cnt[256];
    __shared__ int sh[256];
    __shared__ int pos[256];
    int b = blockIdx.x;
    int t = threadIdx.x;
    int n = bucketCnt[b];
    int bBase = b * BCAP;
    const unsigned* eb = ebuf + (size_t)bBase;
    cnt[t] = 0;
    __syncthreads();
    for (int i = t; i < n; i += 256) atomicAdd(&cnt[eb[i] >> 16], 1);
    __syncthreads();
    int v = cnt[t];
    sh[t] = v;
    __syncthreads();
    for (int off = 1; off < 256; off <<= 1) {
        int x = sh[t];
        if (t >= off) x += sh[t - off];
        __syncthreads();
        sh[t] = x;
        __syncthreads();
    }
    int excl = sh[t] - v;
    pos[t] = excl;
    int node = b * 256 + t;
    if (node < N_NODES) {
        estart[node] = bBase + excl;
        eend[node] = bBase + excl + v;
    }
    __syncthreads();
    for (int i = t; i < n; i += 256) {
        unsigned pe = eb[i];
        int dl = pe >> 16;
        int p = atomicAdd(&pos[dl], 1);
        srcSorted[bBase + p] = (unsigned short)(pe & 0xFFFFu);
    }
}

// ---------------- Fused aggregation + MFMA MLP, BN-scale computed in-kernel ----------------
#define MPITCH 136

template <bool BN>
__global__ __launch_bounds__(256) void k_aggmlp(const unsigned short* __restrict__ X,
                                                const float* __restrict__ bnprev,
                                                const float* __restrict__ gamma,
                                                const float* __restrict__ beta,
                                                const int* __restrict__ estart,
                                                const int* __restrict__ eend,
                                                const unsigned short* __restrict__ srcSorted,
                                                const unsigned short* __restrict__ W1p,
                                                const float* __restrict__ b1,
                                                const unsigned short* __restrict__ W2p,
                                                const float* __restrict__ b2,
                                                unsigned short* __restrict__ hbf,
                                                float* __restrict__ bnout) {
    __shared__ __align__(16) unsigned short As[16 * MPITCH];
    __shared__ __align__(16) unsigned short Ts[16 * MPITCH];

    int tid = threadIdx.x;
    int wave = tid >> 6;
    int lane = tid & 63;
    int lrow = lane & 15;
    int quad = lane >> 4;
    int half = lane >> 5;
    int hl = lane & 31;
    int hq = hl >> 4;
    int rowBase = blockIdx.x * 16;
    int col0 = lrow * 8;

    float scv[8], shv[8];
    if (BN) {
        float* ft = (float*)As;
        float* scs = ft + 256;
        float a = 0.f;
#pragma unroll
        for (int j = 0; j < BN_SLOTS; j++) a += bnprev[j * 256 + tid];
        ft[tid] = a;
        __syncthreads();
        if (tid < HID) {
            float mean = ft[tid] * (1.0f / N_NODES);
            float var = ft[HID + tid] * (1.0f / N_NODES) - mean * mean;
            float s = gamma[tid] * rsqrtf(var + BN_EPS);
            scs[tid] = s;
            scs[HID + tid] = beta[tid] - mean * s;
        }
        __syncthreads();
#pragma unroll
        for (int j = 0; j < 8; j++) { scv[j] = scs[col0 + j]; shv[j] = scs[HID + col0 + j]; }
        __syncthreads();
    }

    // gather chunk processor: idx = this lane's preloaded src index for the chunk,
    // cnt = valid slots (<=16). Loads exec-predicated on slot validity.
    auto do_chunk = [&](float* acc, int idx, int cnt) {
        short8_t v[8];
        int rid[8];
#pragma unroll
        for (int u = 0; u < 8; u++) {
            int slot = u * 2 + hq;
            int sl = slot < cnt ? slot : cnt - 1;
            rid[u] = __shfl(idx, (half << 5) + sl);
        }
#pragma unroll
        for (int u = 0; u < 8; u++) {
            int slot = u * 2 + hq;
            if (slot < cnt)
                v[u] = *(const short8_t*)&X[(size_t)rid[u] * HID + col0];
        }
#pragma unroll
        for (int u = 0; u < 8; u++) {
            int slot = u * 2 + hq;
            if (slot < cnt) {
                uint4 uu = *(uint4*)&v[u];
                float2 p0 = bfp2f(uu.x), p1 = bfp2f(uu.y), p2 = bfp2f(uu.z), p3 = bfp2f(uu.w);
                float f[8] = { p0.x, p0.y, p1.x, p1.y, p2.x, p2.y, p3.x, p3.y };
#pragma unroll
                for (int j = 0; j < 8; j++)
                    acc[j] += BN ? fmaxf(f[j] * scv[j] + shv[j], 0.f) : f[j];
            }
        }
    };

    for (int pr = 0; pr < 2; pr++) {
        int tr = wave * 4 + pr * 2 + half;
        int node = rowBase + tr;
        float acc[8];

        int e0 = estart[node];
        int deg = eend[node] - e0;

        // prefetch both chunks' indices up-front (deg<=32 covers ~99.98%)
        int p0i = hl & 15; if (p0i >= deg) p0i = deg - 1;
        int i0 = (int)srcSorted[e0 + p0i];
        int i1 = i0;
        if (deg > 16) {
            int p1i = 16 + (hl & 15); if (p1i >= deg) p1i = deg - 1;
            i1 = (int)srcSorted[e0 + p1i];
        }

        // own row: only the accumulating slot (hq==0) loads it
        if (hq == 0) {
            short8_t ov = *(const short8_t*)&X[(size_t)node * HID + col0];
            uint4 uu = *(uint4*)&ov;
            float2 q0 = bfp2f(uu.x), q1 = bfp2f(uu.y), q2 = bfp2f(uu.z), q3 = bfp2f(uu.w);
            float f[8] = { q0.x, q0.y, q1.x, q1.y, q2.x, q2.y, q3.x, q3.y };
#pragma unroll
            for (int j = 0; j < 8; j++)
                acc[j] = BN ? fmaxf(f[j] * scv[j] + shv[j], 0.f) : f[j];
        } else {
#pragma unroll
            for (int j = 0; j < 8; j++) acc[j] = 0.f;
        }

        do_chunk(acc, i0, deg < 16 ? deg : 16);
        if (deg > 16) {
            int c2 = deg - 16; if (c2 > 16) c2 = 16;
            do_chunk(acc, i1, c2);
        }
        // rare tail (deg > 32)
        for (int base = 32; base < deg; base += 16) {
            int pp = base + (hl & 15); if (pp >= deg) pp = deg - 1;
            int ii = (int)srcSorted[e0 + pp];
            int cc = deg - base; if (cc > 16) cc = 16;
            do_chunk(acc, ii, cc);
        }

#pragma unroll
        for (int j = 0; j < 8; j++) acc[j] += __shfl_xor(acc[j], 16);
        if (hq == 0) {
            short8_t o;
#pragma unroll
            for (int j = 0; j < 8; j++) o[j] = (short)f2bf(acc[j]);
            *(short8_t*)&As[tr * MPITCH + col0] = o;
        }
    }
    __syncthreads();

    int t0 = wave * 2;
    short8_t a0f = *(const short8_t*)&As[lrow * MPITCH + 0 * 32 + quad * 8];
    short8_t a1f = *(const short8_t*)&As[lrow * MPITCH + 1 * 32 + quad * 8];
    short8_t a2f = *(const short8_t*)&As[lrow * MPITCH + 2 * 32 + quad * 8];
    short8_t a3f = *(const short8_t*)&As[lrow * MPITCH + 3 * 32 + quad * 8];

    f32x4 acc1[2];
#pragma unroll
    for (int ti = 0; ti < 2; ti++) {
        int t = t0 + ti;
        f32x4 a = (f32x4){ 0.f, 0.f, 0.f, 0.f };
        short8_t b0 = *(const short8_t*)&W1p[(size_t)((t * 4 + 0) * 64 + lane) * 8];
        short8_t b1_ = *(const short8_t*)&W1p[(size_t)((t * 4 + 1) * 64 + lane) * 8];
        short8_t b2_ = *(const short8_t*)&W1p[(size_t)((t * 4 + 2) * 64 + lane) * 8];
        short8_t b3 = *(const short8_t*)&W1p[(size_t)((t * 4 + 3) * 64 + lane) * 8];
        a = __builtin_amdgcn_mfma_f32_16x16x32_bf16(a0f, b0, a, 0, 0, 0);
        a = __builtin_amdgcn_mfma_f32_16x16x32_bf16(a1f, b1_, a, 0, 0, 0);
        a = __builtin_amdgcn_mfma_f32_16x16x32_bf16(a2f, b2_, a, 0, 0, 0);
        a = __builtin_amdgcn_mfma_f32_16x16x32_bf16(a3f, b3, a, 0, 0, 0);
        acc1[ti] = a;
    }

#pragma unroll
    for (int ti = 0; ti < 2; ti++) {
        int col = (t0 + ti) * 16 + lrow;
        float bb = b1[col];
#pragma unroll
        for (int r = 0; r < 4; r++) {
            float v = fmaxf(acc1[ti][r] + bb, 0.f);
            Ts[(quad * 4 + r) * MPITCH + col] = f2bf(v);
        }
    }
    __syncthreads();

    short8_t t0f = *(const short8_t*)&Ts[lrow * MPITCH + 0 * 32 + quad * 8];
    short8_t t1f = *(const short8_t*)&Ts[lrow * MPITCH + 1 * 32 + quad * 8];
    short8_t t2f = *(const short8_t*)&Ts[lrow * MPITCH + 2 * 32 + quad * 8];
    short8_t t3f = *(const short8_t*)&Ts[lrow * MPITCH + 3 * 32 + quad * 8];

    f32x4 acc2[2];
#pragma unroll
    for (int ti = 0; ti < 2; ti++) {
        int t = t0 + ti;
        f32x4 a = (f32x4){ 0.f, 0.f, 0.f, 0.f };
        short8_t b0 = *(const short8_t*)&W2p[(size_t)((t * 4 + 0) * 64 + lane) * 8];
        short8_t b1_ = *(const short8_t*)&W2p[(size_t)((t * 4 + 1) * 64 + lane) * 8];
        short8_t b2_ = *(const short8_t*)&W2p[(size_t)((t * 4 + 2) * 64 + lane) * 8];
        short8_t b3 = *(const short8_t*)&W2p[(size_t)((t * 4 + 3) * 64 + lane) * 8];
        a = __builtin_amdgcn_mfma_f32_16x16x32_bf16(t0f, b0, a, 0, 0, 0);
        a = __builtin_amdgcn_mfma_f32_16x16x32_bf16(t1f, b1_, a, 0, 0, 0);
        a = __builtin_amdgcn_mfma_f32_16x16x32_bf16(t2f, b2_, a, 0, 0, 0);
        a = __builtin_amdgcn_mfma_f32_16x16x32_bf16(t3f, b3, a, 0, 0, 0);
        acc2[ti] = a;
    }

#pragma unroll
    for (int ti = 0; ti < 2; ti++) {
        int t = t0 + ti;
        int col = t * 16 + lrow;
        float bb = b2[col];
        float p1 = 0.f, p2 = 0.f;
#pragma unroll
        for (int r = 0; r < 4; r++) {
            unsigned short bv = f2bf(acc2[ti][r] + bb);
            float vr = bf2f(bv);
            p1 += vr; p2 += vr * vr;
            As[(quad * 4 + r) * MPITCH + col] = bv;
        }
        p1 += __shfl_xor(p1, 16); p1 += __shfl_xor(p1, 32);
        p2 += __shfl_xor(p2, 16); p2 += __shfl_xor(p2, 32);
        if (quad == 0) {
            float* bp = bnout + (size_t)(blockIdx.x & (BN_SLOTS - 1)) * 256;
            atomicAdd(&bp[col], p1);
            atomicAdd(&bp[128 + col], p2);
        }
    }
    __syncthreads();

    {
        int r = tid >> 4;
        int c8 = (tid & 15) * 8;
        *(short8_t*)&hbf[(size_t)(rowBase + r) * HID + c8] =
            *(const short8_t*)&As[r * MPITCH + c8];
    }
}

// ---------------- Pool with in-kernel BN finalize + fused BN+ReLU ----------------
#define POOL_CHUNK 512
__global__ void k_pool(const unsigned short* __restrict__ X, const float* __restrict__ bnprev,
                       const float* __restrict__ gamma, const float* __restrict__ beta,
                       const int* __restrict__ batch, float* __restrict__ g) {
    __shared__ float scs[512];
    int t = threadIdx.x;
    {
        float a = 0.f;
#pragma unroll
        for (int j = 0; j < BN_SLOTS; j++) a += bnprev[j * 256 + t];
        scs[t] = a;
        __syncthreads();
        if (t < HID) {
            float mean = scs[t] * (1.0f / N_NODES);
            float var = scs[HID + t] * (1.0f / N_NODES) - mean * mean;
            float s = gamma[t] * rsqrtf(var + BN_EPS);
            float sh = beta[t] - mean * s;
            scs[t] = s;
            scs[HID + t] = sh;
        }
        __syncthreads();
    }
    int lane = t & 31;
    int rg = t >> 5;
    int c = lane * 4;
    float4 s = *(const float4*)&scs[c];
    float4 b = *(const float4*)&scs[HID + c];
    int base = blockIdx.x * POOL_CHUNK;
    int end = base + POOL_CHUNK;
    if (end > N_NODES) end = N_NODES;
    float a0 = 0.f, a1 = 0.f, a2 = 0.f, a3 = 0.f;
    int cur = -1;
    for (int r = base + rg; r < end; r += 8) {
        int bb = batch[r];
        if (bb != cur) {
            if (cur >= 0) {
                atomicAdd(&g[cur * HID + c + 0], a0);
                atomicAdd(&g[cur * HID + c + 1], a1);
                atomicAdd(&g[cur * HID + c + 2], a2);
                atomicAdd(&g[cur * HID + c + 3], a3);
            }
            cur = bb;
            a0 = a1 = a2 = a3 = 0.f;
        }
        ushort4 v = *(const ushort4*)&X[(size_t)r * HID + c];
        a0 += fmaxf(bf2f(v.x) * s.x + b.x, 0.f);
        a1 += fmaxf(bf2f(v.y) * s.y + b.y, 0.f);
        a2 += fmaxf(bf2f(v.z) * s.z + b.z, 0.f);
        a3 += fmaxf(bf2f(v.w) * s.w + b.w, 0.f);
    }
    if (cur >= 0) {
        atomicAdd(&g[cur * HID + c + 0], a0);
        atomicAdd(&g[cur * HID + c + 1], a1);
        atomicAdd(&g[cur * HID + c + 2], a2);
        atomicAdd(&g[cur * HID + c + 3], a3);
    }
}

// ---------------- Final linear ----------------
__global__ void k_final(const float* __restrict__ g, const float* __restrict__ Wlin,
                        const float* __restrict__ blin, float* __restrict__ out) {
    int o = blockIdx.x * 256 + threadIdx.x;
    if (o >= N_GRAPHS * OUTC) return;
    int gi = o / OUTC, c = o % OUTC;
    float s = blin[c];
    for (int k = 0; k < HID; k++) s += g[gi * HID + k] * Wlin[k * OUTC + c];
    out[o] = s;
}

// ---------------- Launch ----------------
extern "C" void kernel_launch(void* const* d_in, const int* in_sizes, int n_in,
                              void* d_out, int out_size, void* d_ws, size_t ws_size,
                              hipStream_t stream) {
    const float* x      = (const float*)d_in[0];
    const float* W1s    = (const float*)d_in[1];
    const float* b1s    = (const float*)d_in[2];
    const float* W2s    = (const float*)d_in[3];
    const float* b2s    = (const float*)d_in[4];
    const float* gammas = (const float*)d_in[5];
    const float* betas  = (const float*)d_in[6];
    const float* Wlin   = (const float*)d_in[7];
    const float* blin   = (const float*)d_in[8];
    const int* edge_index = (const int*)d_in[9];
    const int* batch    = (const int*)d_in[10];
    float* out = (float*)d_out;

    const int* src = edge_index;
    const int* dst = edge_index + N_EDGES;

    char* w = (char*)d_ws;
    // zeroed region (single memset): bucketCnt | bnpart (3 regions) | g
    int* bucketCnt = (int*)w;        w += 256 * 4;
    float* bnpart  = (float*)w;      w += (size_t)3 * BN_REGION * 4;
    float* g       = (float*)w;      w += (size_t)N_GRAPHS * HID * 4;
    size_t zeroBytes = (size_t)(w - (char*)d_ws);
    // rest
    unsigned* ebuf = (unsigned*)w;   w += (size_t)NB * BCAP * 4;
    unsigned short* srcSorted = (unsigned short*)w; w += (size_t)NB * BCAP * 2;
    int* estart    = (int*)w;        w += (size_t)N_NODES * 4;
    int* eend      = (int*)w;        w += (size_t)N_NODES * 4;
    unsigned short* Xbf = (unsigned short*)w; w += (size_t)N_NODES * HID * 2;
    unsigned short* HA  = (unsigned short*)w; w += (size_t)N_NODES * HID * 2;
    unsigned short* HB  = (unsigned short*)w; w += (size_t)N_NODES * HID * 2;
    unsigned short* Wp  = (unsigned short*)w; w += (size_t)6 * 2048 * 8 * 2;

    hipMemsetAsync(d_ws, 0, zeroBytes, stream);

    k_bucketprep<<<NBLK_A + NBLK_PREP, 256, 0, stream>>>(src, dst, bucketCnt, ebuf,
                                                         x, W1s, W2s, Xbf, Wp);
    k_bsort<<<NB, 256, 0, stream>>>(bucketCnt, ebuf, srcSorted, estart, eend);

    // layer 0: Xbf -> HA ; layer 1: HA -> HB ; layer 2: HB -> HA
    const unsigned short* in0 = Xbf;
    unsigned short* outs[3] = { HA, HB, HA };
    for (int l = 0; l < 3; l++) {
        const unsigned short* xin = (l == 0) ? in0 : outs[l - 1];
        float* bnout = bnpart + (size_t)l * BN_REGION;
        if (l == 0)
            k_aggmlp<false><<<MLP_BLOCKS, 256, 0, stream>>>(
                xin, nullptr, nullptr, nullptr, estart, eend, srcSorted,
                Wp + (size_t)(l * 2 + 0) * 16384, b1s + (size_t)l * HID,
                Wp + (size_t)(l * 2 + 1) * 16384, b2s + (size_t)l * HID, outs[l], bnout);
        else
            k_aggmlp<true><<<MLP_BLOCKS, 256, 0, stream>>>(
                xin, bnpart + (size_t)(l - 1) * BN_REGION,
                gammas + (size_t)(l - 1) * HID, betas + (size_t)(l - 1) * HID,
                estart, eend, srcSorted,
                Wp + (size_t)(l * 2 + 0) * 16384, b1s + (size_t)l * HID,
                Wp + (size_t)(l * 2 + 1) * 16384, b2s + (size_t)l * HID, outs[l], bnout);
    }

    k_pool<<<(N_NODES + POOL_CHUNK - 1) / POOL_CHUNK, 256, 0, stream>>>(
        outs[2], bnpart + (size_t)2 * BN_REGION, gammas + (size_t)2 * HID,
        betas + (size_t)2 * HID, batch, g);
    k_final<<<(N_GRAPHS * OUTC + 255) / 256, 256, 0, stream>>>(g, Wlin, blin, out);
}